// Round 8
// baseline (681.705 us; speedup 1.0000x reference)
//
#include <hip/hip_runtime.h>
#include <hip/hip_bf16.h>

#define N_NODES 200000
#define N_EDGES 640000
#define D_NODE 128
#define D_EDGE 32
#define HIDDEN 128
#define KTOT 288          // 128 (x) + 128 (Sx) + 32 (Sea)

using bf16x8  = __attribute__((ext_vector_type(8))) short;
using f32x4   = __attribute__((ext_vector_type(4))) float;
using short4v = __attribute__((ext_vector_type(4))) short;

__device__ __forceinline__ short f2b(float f) {
  return __builtin_bit_cast(short, __float2bfloat16(f));
}
__device__ __forceinline__ float b2f(short s) {
  unsigned u = ((unsigned)(unsigned short)s) << 16;
  return __builtin_bit_cast(float, u);
}

// ===========================================================================
// k_prep: one launch, three block ranges
//   [0, 12500)      : AF[:,0:128] = bf16(x)
//   [12500, 15000)  : hist  (slot[e] = atomicAdd(cnt[dst], 1))
//   [15000, 15145)  : WcT = bf16([W2_top ; W1@W2_bot]^T), bc = b1@W2_bot
// ===========================================================================
#define PREP_NB 12500   // N_NODES*16/256
#define HIST_NB 2500    // N_EDGES/256
#define WC_NB   145     // ceil((288*128 + 128)/256)

__global__ __launch_bounds__(256) void k_prep(
    const float* __restrict__ x, short* __restrict__ AF,
    const int* __restrict__ ei, int* cnt, int* slot,
    const float* __restrict__ W1, const float* __restrict__ b1,
    const float* __restrict__ W2, short* __restrict__ WcT,
    float* __restrict__ bc)
{
  const int b = blockIdx.x;
  if (b < PREP_NB) {
    const int i = b * 256 + threadIdx.x;
    const int node = i >> 4;
    const int oct  = (i & 15) << 3;
    const float4 v0 = *(const float4*)&x[(size_t)node * D_NODE + oct];
    const float4 v1 = *(const float4*)&x[(size_t)node * D_NODE + oct + 4];
    bf16x8 o = { f2b(v0.x), f2b(v0.y), f2b(v0.z), f2b(v0.w),
                 f2b(v1.x), f2b(v1.y), f2b(v1.z), f2b(v1.w) };
    *(bf16x8*)&AF[(size_t)node * KTOT + oct] = o;
  } else if (b < PREP_NB + HIST_NB) {
    const int e = (b - PREP_NB) * 256 + threadIdx.x;
    slot[e] = atomicAdd(&cnt[ei[N_EDGES + e]], 1);
  } else {
    const int t = (b - PREP_NB - HIST_NB) * 256 + threadIdx.x;
    if (t < 288 * 128) {
      const int brow = t >> 7, c = t & 127;
      if (brow < 128) {
        WcT[c * KTOT + brow] = f2b(W2[brow * 128 + c]);
      } else {
        const int i = brow - 128;
        float acc = 0.f;
        #pragma unroll 8
        for (int q = 0; q < 128; ++q)
          acc += W1[i * 128 + q] * W2[(128 + q) * 128 + c];
        WcT[c * KTOT + brow] = f2b(acc);
      }
    } else if (t < 288 * 128 + 128) {
      const int c = t - 288 * 128;
      float acc = 0.f;
      #pragma unroll 8
      for (int q = 0; q < 128; ++q)
        acc += b1[q] * W2[(128 + q) * 128 + c];
      bc[c] = acc;
    }
  }
}

// ===========================================================================
// CSR: scan_a (per-1024 block sums) -> scan_c2 (self-computed prefix) -> place
// ===========================================================================
#define SCAN_NB 196  // ceil(200000/1024)

__global__ __launch_bounds__(256) void k_scan_a(const int* __restrict__ cnt,
                                                int* bsum) {
  __shared__ int sh[256];
  const int b = blockIdx.x, t = threadIdx.x;
  const int base = b * 1024 + t * 4;
  int s = 0;
  #pragma unroll
  for (int k = 0; k < 4; ++k) {
    const int idx = base + k;
    s += (idx < N_NODES) ? cnt[idx] : 0;
  }
  sh[t] = s; __syncthreads();
  for (int o = 128; o > 0; o >>= 1) {
    if (t < o) sh[t] += sh[t + o];
    __syncthreads();
  }
  if (t == 0) bsum[b] = sh[0];
}

__global__ __launch_bounds__(256) void k_scan_c2(const int* __restrict__ cnt,
                                                 const int* __restrict__ bsum,
                                                 int* offv) {
  __shared__ int sh[256];
  __shared__ int base_sh;
  const int b = blockIdx.x, t = threadIdx.x;

  sh[t] = (t < SCAN_NB && t < b) ? bsum[t] : 0;
  __syncthreads();
  for (int o = 128; o > 0; o >>= 1) {
    if (t < o) sh[t] += sh[t + o];
    __syncthreads();
  }
  if (t == 0) base_sh = sh[0];
  __syncthreads();

  const int base = b * 1024 + t * 4;
  int v[4], p[4], s = 0;
  #pragma unroll
  for (int k = 0; k < 4; ++k) {
    const int idx = base + k;
    v[k] = (idx < N_NODES) ? cnt[idx] : 0;
    p[k] = s; s += v[k];
  }
  sh[t] = s; __syncthreads();
  const int tot = s;
  for (int o = 1; o < 256; o <<= 1) {
    const int tv = (t >= o) ? sh[t - o] : 0;
    __syncthreads();
    sh[t] += tv;
    __syncthreads();
  }
  const int gb = base_sh + (sh[t] - tot);
  #pragma unroll
  for (int k = 0; k < 4; ++k) {
    const int idx = base + k;
    if (idx < N_NODES) offv[idx] = gb + p[k];
  }
}

// pr[j] = { src | (dst&31)<<18 , edge_id }.  Valid: src < 2^18, sagg blocks
// own 32-aligned node ranges so dst_local = dst & 31.
__global__ __launch_bounds__(256) void k_place4(const int* __restrict__ ei,
                                                const int* __restrict__ offv,
                                                const int* __restrict__ slot,
                                                int2* __restrict__ pr) {
  const int e = blockIdx.x * 256 + threadIdx.x;
  if (e < N_EDGES) {
    const int dst = ei[N_EDGES + e];
    const int j = offv[dst] + slot[e];
    int2 v;
    v.x = ei[e] | ((dst & 31) << 18);
    v.y = e;
    pr[j] = v;
  }
}

// ===========================================================================
// S aggregation, edge-parallel with block-local LDS accumulation.
//   Block owns nodes [b*32, b*32+32) and their contiguous slot range.
//   Pass 1: 16 threads/slot gather AF x-rows -> LDS atomicAdd (acc[dl][0:128))
//   Pass 2:  8 threads/slot gather ea rows   -> LDS atomicAdd (acc[dl][128:160))
//   Writeback: acc -> bf16 AF cols 128+c.  Perfect edge balance, no max-of-4.
// ===========================================================================
#define SG_NB 32
#define SG_LD 168   // f32 pad: stride 168 % 32 = 8 banks -> spread

__global__ __launch_bounds__(256) void k_sagg2(
    const float* __restrict__ ea, const int* __restrict__ offv,
    const int2* __restrict__ pr, short* __restrict__ AF)
{
  __shared__ float acc[SG_NB][SG_LD];   // 21504 B
  const int tid = threadIdx.x;
  const int b   = blockIdx.x;
  const int n0  = b * SG_NB;
  const int jlo = offv[n0];
  const int jhi = (b == (N_NODES / SG_NB) - 1) ? N_EDGES : offv[n0 + SG_NB];
  const int count = jhi - jlo;

  for (int i = tid; i < SG_NB * SG_LD; i += 256) ((float*)acc)[i] = 0.f;
  __syncthreads();

  // pass 1: x-part (16 threads per slot, 8 bf16 each)
  for (int idx = tid; idx < count * 16; idx += 256) {
    const int j   = jlo + (idx >> 4);
    const int oct = (idx & 15) << 3;
    const int2 w  = pr[j];
    const int src = w.x & 0x3FFFF;
    const int dl  = (w.x >> 18) & 31;
    const bf16x8 v = *(const bf16x8*)&AF[(size_t)src * KTOT + oct];
    #pragma unroll
    for (int k = 0; k < 8; ++k)
      atomicAdd(&acc[dl][oct + k], b2f(v[k]));
  }
  // pass 2: ea-part (8 threads per slot, 4 f32 each)
  for (int idx = tid; idx < count * 8; idx += 256) {
    const int j  = jlo + (idx >> 3);
    const int q  = (idx & 7) << 2;
    const int2 w = pr[j];
    const int dl = (w.x >> 18) & 31;
    const float4 v = *(const float4*)&ea[(size_t)w.y * D_EDGE + q];
    atomicAdd(&acc[dl][128 + q + 0], v.x);
    atomicAdd(&acc[dl][128 + q + 1], v.y);
    atomicAdd(&acc[dl][128 + q + 2], v.z);
    atomicAdd(&acc[dl][128 + q + 3], v.w);
  }
  __syncthreads();

  // writeback: 32 nodes x 20 octs; AF col = 128 + c for c in [0,160)
  for (int i = tid; i < SG_NB * 20; i += 256) {
    const int m  = i / 20;
    const int c8 = (i % 20) << 3;
    bf16x8 v;
    #pragma unroll
    for (int k = 0; k < 8; ++k) v[k] = f2b(acc[m][c8 + k]);
    *(bf16x8*)&AF[(size_t)(n0 + m) * KTOT + 128 + c8] = v;
  }
}

// ===========================================================================
// Output GEMM: out = AF @ Wc + cnt*bc + b2.
//   BM=64 (grid 3125, exact), K=288 in 3x96 phases, LDS 39.9KB -> 4 blocks/CU.
//   Epilogue via LDS -> coalesced float4 row stores.  (round-5/7 proven)
// ===========================================================================
#define LDP 104   // 96+8 bf16: 208B rows -> 2-way bank alias only (free)

__global__ __launch_bounds__(256, 4) void k_out2(
    const short* __restrict__ AF, const short* __restrict__ WcT,
    const float* __restrict__ bc, const float* __restrict__ b2,
    const int* __restrict__ cnt, float* __restrict__ out)
{
  __shared__ short smem[64 * LDP + 128 * LDP];   // 39936 B
  short* lA = smem;
  short* lB = smem + 64 * LDP;
  const int tid = threadIdx.x;
  const int n0  = blockIdx.x * 64;

  const int lane = tid & 63;
  const int wid  = tid >> 6;
  const int wm = wid >> 1, wn = wid & 1;          // 2x2 waves, 32x64 out each
  const int lrow = lane & 15;
  const int lk   = (lane >> 4) << 3;

  f32x4 acc[2][4] = {};

  #pragma unroll
  for (int p = 0; p < 3; ++p) {
    for (int i = tid; i < 1536; i += 256) {       // lB: 128 rows x 12 octs
      const int n = i / 12, ck = (i % 12) << 3;
      *(bf16x8*)&lB[n * LDP + ck] = *(const bf16x8*)&WcT[n * KTOT + p * 96 + ck];
    }
    for (int i = tid; i < 768; i += 256) {        // lA: 64 rows x 12 octs
      const int m = i / 12, ck = (i % 12) << 3;
      *(bf16x8*)&lA[m * LDP + ck] = *(const bf16x8*)&AF[(size_t)(n0 + m) * KTOT + p * 96 + ck];
    }
    __syncthreads();
    #pragma unroll
    for (int kt = 0; kt < 3; ++kt) {
      const int ks = kt * 32 + lk;
      bf16x8 af[2], bfr[4];
      #pragma unroll
      for (int i = 0; i < 2; ++i)
        af[i]  = *(const bf16x8*)&lA[(wm * 32 + i * 16 + lrow) * LDP + ks];
      #pragma unroll
      for (int j = 0; j < 4; ++j)
        bfr[j] = *(const bf16x8*)&lB[(wn * 64 + j * 16 + lrow) * LDP + ks];
      #pragma unroll
      for (int i = 0; i < 2; ++i)
        #pragma unroll
        for (int j = 0; j < 4; ++j)
          acc[i][j] = __builtin_amdgcn_mfma_f32_16x16x32_bf16(af[i], bfr[j], acc[i][j], 0, 0, 0);
    }
    __syncthreads();
  }

  // ---- epilogue: acc + cnt*bc + b2 -> LDS f32 [64][128] -> coalesced stores
  float* lf = (float*)smem;                       // 32768 B <= 39936 B
  const int rb = wm * 32 + ((lane >> 4) << 2);
  const int cb = wn * 64 + lrow;
  float bcv[4], b2v[4];
  #pragma unroll
  for (int j = 0; j < 4; ++j) {
    bcv[j] = bc[cb + j * 16];
    b2v[j] = b2[cb + j * 16];
  }
  #pragma unroll
  for (int i = 0; i < 2; ++i) {
    #pragma unroll
    for (int r = 0; r < 4; ++r) {
      const int row = rb + i * 16 + r;
      const float cf = (float)cnt[n0 + row];
      #pragma unroll
      for (int j = 0; j < 4; ++j)
        lf[row * 128 + cb + j * 16] = acc[i][j][r] + cf * bcv[j] + b2v[j];
    }
  }
  __syncthreads();
  #pragma unroll
  for (int u = 0; u < 8; ++u) {
    const int idx = tid + u * 256;                // 2048 float4s
    const int row = idx >> 5, f4 = (idx & 31) << 2;
    *(float4*)&out[(size_t)(n0 + row) * HIDDEN + f4] = *(const float4*)&lf[row * 128 + f4];
  }
}

extern "C" void kernel_launch(void* const* d_in, const int* in_sizes, int n_in,
                              void* d_out, int out_size, void* d_ws, size_t ws_size,
                              hipStream_t stream) {
  const float* x  = (const float*)d_in[0];
  const int*   ei = (const int*)d_in[1];
  const float* ea = (const float*)d_in[2];
  const float* W1 = (const float*)d_in[5];
  const float* b1 = (const float*)d_in[6];
  const float* W2 = (const float*)d_in[7];
  const float* b2 = (const float*)d_in[8];
  float* out = (float*)d_out;

  const size_t AF_B   = (size_t)N_NODES * KTOT * 2;   // 115,200,000
  const size_t WCT_B  = 128 * KTOT * 2;               //      73,728
  const size_t BC_B   = 512;
  const size_t CNT_B  = (size_t)N_NODES * 4;          //     800,000
  const size_t SLOT_B = (size_t)N_EDGES * 4;          //   2,560,000
  const size_t PR_B   = (size_t)N_EDGES * 8;          //   5,120,000

  const size_t o_AF   = 0;
  const size_t o_wct  = o_AF + AF_B;
  const size_t o_bc   = o_wct + WCT_B;
  const size_t o_cnt  = o_bc + BC_B;
  const size_t o_off  = o_cnt + CNT_B;
  const size_t o_slot = o_off + CNT_B;
  const size_t o_pr   = o_slot + SLOT_B;
  const size_t o_bsum = o_pr + PR_B;
  // total ~124.5 MB (round-7 plan fit)

  short* AF   = (short*)((char*)d_ws + o_AF);
  short* WcT  = (short*)((char*)d_ws + o_wct);
  float* bc   = (float*)((char*)d_ws + o_bc);
  int*   cnt  = (int*)((char*)d_ws + o_cnt);
  int*   offv = (int*)((char*)d_ws + o_off);
  int*   slot = (int*)((char*)d_ws + o_slot);
  int2*  pr   = (int2*)((char*)d_ws + o_pr);
  int*   bsum = (int*)((char*)d_ws + o_bsum);

  hipMemsetAsync(cnt, 0, CNT_B, stream);
  k_prep<<<PREP_NB + HIST_NB + WC_NB, 256, 0, stream>>>(
      x, AF, ei, cnt, slot, W1, b1, W2, WcT, bc);

  k_scan_a <<<SCAN_NB, 256, 0, stream>>>(cnt, bsum);
  k_scan_c2<<<SCAN_NB, 256, 0, stream>>>(cnt, bsum, offv);
  k_place4 <<<(N_EDGES + 255) / 256, 256, 0, stream>>>(ei, offv, slot, pr);

  k_sagg2<<<N_NODES / SG_NB, 256, 0, stream>>>(ea, offv, pr, AF);
  k_out2 <<<N_NODES / 64, 256, 0, stream>>>(AF, WcT, bc, b2, cnt, out);
}

// Round 9
// 271.694 us; speedup vs baseline: 2.5091x; 2.5091x over previous
//
#include <hip/hip_runtime.h>
#include <hip/hip_bf16.h>

#define N_NODES 200000
#define N_EDGES 640000
#define D_NODE 128
#define D_EDGE 32
#define HIDDEN 128
#define KTOT 288          // 128 (x) + 128 (Sx) + 32 (Sea)

using bf16x8  = __attribute__((ext_vector_type(8))) short;
using f32x4   = __attribute__((ext_vector_type(4))) float;
using short4v = __attribute__((ext_vector_type(4))) short;

__device__ __forceinline__ short f2b(float f) {
  return __builtin_bit_cast(short, __float2bfloat16(f));
}
__device__ __forceinline__ float b2f(short s) {
  unsigned u = ((unsigned)(unsigned short)s) << 16;
  return __builtin_bit_cast(float, u);
}

// ===========================================================================
// k_prep: one launch, three block ranges
//   [0, 12500)      : AF[:,0:128] = bf16(x)
//   [12500, 15000)  : hist  (slot[e] = atomicAdd(cnt[dst], 1))
//   [15000, 15145)  : WcT = bf16([W2_top ; W1@W2_bot]^T), bc = b1@W2_bot
// ===========================================================================
#define PREP_NB 12500   // N_NODES*16/256
#define HIST_NB 2500    // N_EDGES/256
#define WC_NB   145     // ceil((288*128 + 128)/256)

__global__ __launch_bounds__(256) void k_prep(
    const float* __restrict__ x, short* __restrict__ AF,
    const int* __restrict__ ei, int* cnt, int* slot,
    const float* __restrict__ W1, const float* __restrict__ b1,
    const float* __restrict__ W2, short* __restrict__ WcT,
    float* __restrict__ bc)
{
  const int b = blockIdx.x;
  if (b < PREP_NB) {
    const int i = b * 256 + threadIdx.x;
    const int node = i >> 4;
    const int oct  = (i & 15) << 3;
    const float4 v0 = *(const float4*)&x[(size_t)node * D_NODE + oct];
    const float4 v1 = *(const float4*)&x[(size_t)node * D_NODE + oct + 4];
    bf16x8 o = { f2b(v0.x), f2b(v0.y), f2b(v0.z), f2b(v0.w),
                 f2b(v1.x), f2b(v1.y), f2b(v1.z), f2b(v1.w) };
    *(bf16x8*)&AF[(size_t)node * KTOT + oct] = o;
  } else if (b < PREP_NB + HIST_NB) {
    const int e = (b - PREP_NB) * 256 + threadIdx.x;
    slot[e] = atomicAdd(&cnt[ei[N_EDGES + e]], 1);
  } else {
    const int t = (b - PREP_NB - HIST_NB) * 256 + threadIdx.x;
    if (t < 288 * 128) {
      const int brow = t >> 7, c = t & 127;
      if (brow < 128) {
        WcT[c * KTOT + brow] = f2b(W2[brow * 128 + c]);
      } else {
        const int i = brow - 128;
        float acc = 0.f;
        #pragma unroll 8
        for (int q = 0; q < 128; ++q)
          acc += W1[i * 128 + q] * W2[(128 + q) * 128 + c];
        WcT[c * KTOT + brow] = f2b(acc);
      }
    } else if (t < 288 * 128 + 128) {
      const int c = t - 288 * 128;
      float acc = 0.f;
      #pragma unroll 8
      for (int q = 0; q < 128; ++q)
        acc += b1[q] * W2[(128 + q) * 128 + c];
      bc[c] = acc;
    }
  }
}

// ===========================================================================
// CSR: scan_a (per-1024 block sums) -> scan_c2 (self-computed prefix) -> place
// ===========================================================================
#define SCAN_NB 196  // ceil(200000/1024)

__global__ __launch_bounds__(256) void k_scan_a(const int* __restrict__ cnt,
                                                int* bsum) {
  __shared__ int sh[256];
  const int b = blockIdx.x, t = threadIdx.x;
  const int base = b * 1024 + t * 4;
  int s = 0;
  #pragma unroll
  for (int k = 0; k < 4; ++k) {
    const int idx = base + k;
    s += (idx < N_NODES) ? cnt[idx] : 0;
  }
  sh[t] = s; __syncthreads();
  for (int o = 128; o > 0; o >>= 1) {
    if (t < o) sh[t] += sh[t + o];
    __syncthreads();
  }
  if (t == 0) bsum[b] = sh[0];
}

__global__ __launch_bounds__(256) void k_scan_c2(const int* __restrict__ cnt,
                                                 const int* __restrict__ bsum,
                                                 int* offv) {
  __shared__ int sh[256];
  __shared__ int base_sh;
  const int b = blockIdx.x, t = threadIdx.x;

  sh[t] = (t < SCAN_NB && t < b) ? bsum[t] : 0;
  __syncthreads();
  for (int o = 128; o > 0; o >>= 1) {
    if (t < o) sh[t] += sh[t + o];
    __syncthreads();
  }
  if (t == 0) base_sh = sh[0];
  __syncthreads();

  const int base = b * 1024 + t * 4;
  int v[4], p[4], s = 0;
  #pragma unroll
  for (int k = 0; k < 4; ++k) {
    const int idx = base + k;
    v[k] = (idx < N_NODES) ? cnt[idx] : 0;
    p[k] = s; s += v[k];
  }
  sh[t] = s; __syncthreads();
  const int tot = s;
  for (int o = 1; o < 256; o <<= 1) {
    const int tv = (t >= o) ? sh[t - o] : 0;
    __syncthreads();
    sh[t] += tv;
    __syncthreads();
  }
  const int gb = base_sh + (sh[t] - tot);
  #pragma unroll
  for (int k = 0; k < 4; ++k) {
    const int idx = base + k;
    if (idx < N_NODES) offv[idx] = gb + p[k];
  }
}

// pr[j] = { src_row, edge_id } as one 8B store
__global__ __launch_bounds__(256) void k_place3(const int* __restrict__ ei,
                                                const int* __restrict__ offv,
                                                const int* __restrict__ slot,
                                                int2* __restrict__ pr) {
  const int e = blockIdx.x * 256 + threadIdx.x;
  if (e < N_EDGES) {
    const int j = offv[ei[N_EDGES + e]] + slot[e];
    int2 v; v.x = ei[e]; v.y = e;
    pr[j] = v;
  }
}

// ===========================================================================
// S aggregation, wave-per-node, register accumulation + shuffle reduce.
//   blocks [0, 50000)      : x-part.  Wave = 1 node; lane = (sg:2 | oct:4).
//     lane accumulates AF[src][oct*8..+8) over slots j = s0+sg step 4;
//     shfl_xor(16,32) combines the 4 slot-groups; sg==0 lanes store 256B row.
//   blocks [50000, 100000) : ea-part. lane = (sg:3 | q:3), slots step 8,
//     shfl_xor(8,16,32), sg==0 lanes store 64B.
//   No atomics anywhere; imbalance = E[ceil(len/4)] (~1.3) not E[max4] (~5.6).
// ===========================================================================
#define SGX_NB 50000   // N_NODES/4 waves-per-block
#define SGE_NB 50000

__global__ __launch_bounds__(256) void k_sagg3(
    const float* __restrict__ ea, const int* __restrict__ offv,
    const int* __restrict__ cnt, const int2* __restrict__ pr,
    short* __restrict__ AF)
{
  const int b    = blockIdx.x;
  const int lane = threadIdx.x & 63;
  if (b < SGX_NB) {
    const int node = b * 4 + (threadIdx.x >> 6);
    const int oct8 = (lane & 15) << 3;
    const int sg   = lane >> 4;              // 0..3
    const int s0 = offv[node];
    const int s1 = s0 + cnt[node];
    float a[8] = {};
    for (int j = s0 + sg; j < s1; j += 4) {
      const int src = pr[j].x;
      const bf16x8 v = *(const bf16x8*)&AF[(size_t)src * KTOT + oct8];
      #pragma unroll
      for (int k = 0; k < 8; ++k) a[k] += b2f(v[k]);
    }
    #pragma unroll
    for (int k = 0; k < 8; ++k) {
      a[k] += __shfl_xor(a[k], 16);
      a[k] += __shfl_xor(a[k], 32);
    }
    if (sg == 0) {
      bf16x8 o;
      #pragma unroll
      for (int k = 0; k < 8; ++k) o[k] = f2b(a[k]);
      *(bf16x8*)&AF[(size_t)node * KTOT + 128 + oct8] = o;
    }
  } else {
    const int node = (b - SGX_NB) * 4 + (threadIdx.x >> 6);
    const int q    = (lane & 7) << 2;
    const int sg   = lane >> 3;              // 0..7
    const int s0 = offv[node];
    const int s1 = s0 + cnt[node];
    float a0 = 0.f, a1 = 0.f, a2 = 0.f, a3 = 0.f;
    for (int j = s0 + sg; j < s1; j += 8) {
      const float4 v = *(const float4*)&ea[(size_t)pr[j].y * D_EDGE + q];
      a0 += v.x; a1 += v.y; a2 += v.z; a3 += v.w;
    }
    #pragma unroll
    for (int m = 8; m <= 32; m <<= 1) {
      a0 += __shfl_xor(a0, m);
      a1 += __shfl_xor(a1, m);
      a2 += __shfl_xor(a2, m);
      a3 += __shfl_xor(a3, m);
    }
    if (sg == 0) {
      short4v o = { f2b(a0), f2b(a1), f2b(a2), f2b(a3) };
      *(short4v*)&AF[(size_t)node * KTOT + 256 + q] = o;
    }
  }
}

// ===========================================================================
// Output GEMM: out = AF @ Wc + cnt*bc + b2.
//   BM=64 (grid 3125, exact), K=288 in 3x96 phases, LDS 39.9KB -> 4 blocks/CU.
//   Epilogue via LDS -> coalesced float4 row stores.  (round-5/7 proven)
// ===========================================================================
#define LDP 104   // 96+8 bf16: 208B rows -> 2-way bank alias only (free)

__global__ __launch_bounds__(256, 4) void k_out2(
    const short* __restrict__ AF, const short* __restrict__ WcT,
    const float* __restrict__ bc, const float* __restrict__ b2,
    const int* __restrict__ cnt, float* __restrict__ out)
{
  __shared__ short smem[64 * LDP + 128 * LDP];   // 39936 B
  short* lA = smem;
  short* lB = smem + 64 * LDP;
  const int tid = threadIdx.x;
  const int n0  = blockIdx.x * 64;

  const int lane = tid & 63;
  const int wid  = tid >> 6;
  const int wm = wid >> 1, wn = wid & 1;          // 2x2 waves, 32x64 out each
  const int lrow = lane & 15;
  const int lk   = (lane >> 4) << 3;

  f32x4 acc[2][4] = {};

  #pragma unroll
  for (int p = 0; p < 3; ++p) {
    for (int i = tid; i < 1536; i += 256) {       // lB: 128 rows x 12 octs
      const int n = i / 12, ck = (i % 12) << 3;
      *(bf16x8*)&lB[n * LDP + ck] = *(const bf16x8*)&WcT[n * KTOT + p * 96 + ck];
    }
    for (int i = tid; i < 768; i += 256) {        // lA: 64 rows x 12 octs
      const int m = i / 12, ck = (i % 12) << 3;
      *(bf16x8*)&lA[m * LDP + ck] = *(const bf16x8*)&AF[(size_t)(n0 + m) * KTOT + p * 96 + ck];
    }
    __syncthreads();
    #pragma unroll
    for (int kt = 0; kt < 3; ++kt) {
      const int ks = kt * 32 + lk;
      bf16x8 af[2], bfr[4];
      #pragma unroll
      for (int i = 0; i < 2; ++i)
        af[i]  = *(const bf16x8*)&lA[(wm * 32 + i * 16 + lrow) * LDP + ks];
      #pragma unroll
      for (int j = 0; j < 4; ++j)
        bfr[j] = *(const bf16x8*)&lB[(wn * 64 + j * 16 + lrow) * LDP + ks];
      #pragma unroll
      for (int i = 0; i < 2; ++i)
        #pragma unroll
        for (int j = 0; j < 4; ++j)
          acc[i][j] = __builtin_amdgcn_mfma_f32_16x16x32_bf16(af[i], bfr[j], acc[i][j], 0, 0, 0);
    }
    __syncthreads();
  }

  // ---- epilogue: acc + cnt*bc + b2 -> LDS f32 [64][128] -> coalesced stores
  float* lf = (float*)smem;                       // 32768 B <= 39936 B
  const int rb = wm * 32 + ((lane >> 4) << 2);
  const int cb = wn * 64 + lrow;
  float bcv[4], b2v[4];
  #pragma unroll
  for (int j = 0; j < 4; ++j) {
    bcv[j] = bc[cb + j * 16];
    b2v[j] = b2[cb + j * 16];
  }
  #pragma unroll
  for (int i = 0; i < 2; ++i) {
    #pragma unroll
    for (int r = 0; r < 4; ++r) {
      const int row = rb + i * 16 + r;
      const float cf = (float)cnt[n0 + row];
      #pragma unroll
      for (int j = 0; j < 4; ++j)
        lf[row * 128 + cb + j * 16] = acc[i][j][r] + cf * bcv[j] + b2v[j];
    }
  }
  __syncthreads();
  #pragma unroll
  for (int u = 0; u < 8; ++u) {
    const int idx = tid + u * 256;                // 2048 float4s
    const int row = idx >> 5, f4 = (idx & 31) << 2;
    *(float4*)&out[(size_t)(n0 + row) * HIDDEN + f4] = *(const float4*)&lf[row * 128 + f4];
  }
}

extern "C" void kernel_launch(void* const* d_in, const int* in_sizes, int n_in,
                              void* d_out, int out_size, void* d_ws, size_t ws_size,
                              hipStream_t stream) {
  const float* x  = (const float*)d_in[0];
  const int*   ei = (const int*)d_in[1];
  const float* ea = (const float*)d_in[2];
  const float* W1 = (const float*)d_in[5];
  const float* b1 = (const float*)d_in[6];
  const float* W2 = (const float*)d_in[7];
  const float* b2 = (const float*)d_in[8];
  float* out = (float*)d_out;

  const size_t AF_B   = (size_t)N_NODES * KTOT * 2;   // 115,200,000
  const size_t WCT_B  = 128 * KTOT * 2;               //      73,728
  const size_t BC_B   = 512;
  const size_t CNT_B  = (size_t)N_NODES * 4;          //     800,000
  const size_t SLOT_B = (size_t)N_EDGES * 4;          //   2,560,000
  const size_t PR_B   = (size_t)N_EDGES * 8;          //   5,120,000

  const size_t o_AF   = 0;
  const size_t o_wct  = o_AF + AF_B;
  const size_t o_bc   = o_wct + WCT_B;
  const size_t o_cnt  = o_bc + BC_B;
  const size_t o_off  = o_cnt + CNT_B;
  const size_t o_slot = o_off + CNT_B;
  const size_t o_pr   = o_slot + SLOT_B;
  const size_t o_bsum = o_pr + PR_B;
  // total ~124.5 MB (round-7 plan fit)

  short* AF   = (short*)((char*)d_ws + o_AF);
  short* WcT  = (short*)((char*)d_ws + o_wct);
  float* bc   = (float*)((char*)d_ws + o_bc);
  int*   cnt  = (int*)((char*)d_ws + o_cnt);
  int*   offv = (int*)((char*)d_ws + o_off);
  int*   slot = (int*)((char*)d_ws + o_slot);
  int2*  pr   = (int2*)((char*)d_ws + o_pr);
  int*   bsum = (int*)((char*)d_ws + o_bsum);

  hipMemsetAsync(cnt, 0, CNT_B, stream);
  k_prep<<<PREP_NB + HIST_NB + WC_NB, 256, 0, stream>>>(
      x, AF, ei, cnt, slot, W1, b1, W2, WcT, bc);

  k_scan_a <<<SCAN_NB, 256, 0, stream>>>(cnt, bsum);
  k_scan_c2<<<SCAN_NB, 256, 0, stream>>>(cnt, bsum, offv);
  k_place3 <<<(N_EDGES + 255) / 256, 256, 0, stream>>>(ei, offv, slot, pr);

  k_sagg3<<<SGX_NB + SGE_NB, 256, 0, stream>>>(ea, offv, cnt, pr, AF);
  k_out2 <<<N_NODES / 64, 256, 0, stream>>>(AF, WcT, bc, b2, cnt, out);
}

// Round 10
// 224.630 us; speedup vs baseline: 3.0348x; 1.2095x over previous
//
#include <hip/hip_runtime.h>
#include <hip/hip_bf16.h>

#define N_NODES 200000
#define N_EDGES 640000
#define D_NODE 128
#define D_EDGE 32
#define HIDDEN 128
#define KTOT 288          // 128 (x) + 128 (Sx) + 32 (Sea)

using bf16x8  = __attribute__((ext_vector_type(8))) short;
using f32x4   = __attribute__((ext_vector_type(4))) float;
using short4v = __attribute__((ext_vector_type(4))) short;

__device__ __forceinline__ short f2b(float f) {
  return __builtin_bit_cast(short, __float2bfloat16(f));
}
__device__ __forceinline__ float b2f(short s) {
  unsigned u = ((unsigned)(unsigned short)s) << 16;
  return __builtin_bit_cast(float, u);
}

// ===========================================================================
// k_prep: one launch, three block ranges
//   [0, 12500)      : AF[:,0:128] = bf16(x)
//   [12500, 15000)  : hist  (slot[e] = atomicAdd(cnt[dst], 1))
//   [15000, 15145)  : WcT = bf16([W2_top ; W1@W2_bot]^T), bc = b1@W2_bot
// ===========================================================================
#define PREP_NB 12500   // N_NODES*16/256
#define HIST_NB 2500    // N_EDGES/256
#define WC_NB   145     // ceil((288*128 + 128)/256)

__global__ __launch_bounds__(256) void k_prep(
    const float* __restrict__ x, short* __restrict__ AF,
    const int* __restrict__ ei, int* cnt, int* slot,
    const float* __restrict__ W1, const float* __restrict__ b1,
    const float* __restrict__ W2, short* __restrict__ WcT,
    float* __restrict__ bc)
{
  const int b = blockIdx.x;
  if (b < PREP_NB) {
    const int i = b * 256 + threadIdx.x;
    const int node = i >> 4;
    const int oct  = (i & 15) << 3;
    const float4 v0 = *(const float4*)&x[(size_t)node * D_NODE + oct];
    const float4 v1 = *(const float4*)&x[(size_t)node * D_NODE + oct + 4];
    bf16x8 o = { f2b(v0.x), f2b(v0.y), f2b(v0.z), f2b(v0.w),
                 f2b(v1.x), f2b(v1.y), f2b(v1.z), f2b(v1.w) };
    *(bf16x8*)&AF[(size_t)node * KTOT + oct] = o;
  } else if (b < PREP_NB + HIST_NB) {
    const int e = (b - PREP_NB) * 256 + threadIdx.x;
    slot[e] = atomicAdd(&cnt[ei[N_EDGES + e]], 1);
  } else {
    const int t = (b - PREP_NB - HIST_NB) * 256 + threadIdx.x;
    if (t < 288 * 128) {
      const int brow = t >> 7, c = t & 127;
      if (brow < 128) {
        WcT[c * KTOT + brow] = f2b(W2[brow * 128 + c]);
      } else {
        const int i = brow - 128;
        float acc = 0.f;
        #pragma unroll 8
        for (int q = 0; q < 128; ++q)
          acc += W1[i * 128 + q] * W2[(128 + q) * 128 + c];
        WcT[c * KTOT + brow] = f2b(acc);
      }
    } else if (t < 288 * 128 + 128) {
      const int c = t - 288 * 128;
      float acc = 0.f;
      #pragma unroll 8
      for (int q = 0; q < 128; ++q)
        acc += b1[q] * W2[(128 + q) * 128 + c];
      bc[c] = acc;
    }
  }
}

// ===========================================================================
// CSR: scan_a (per-1024 block sums) -> scan_c2 (self-computed prefix) -> place
// ===========================================================================
#define SCAN_NB 196  // ceil(200000/1024)

__global__ __launch_bounds__(256) void k_scan_a(const int* __restrict__ cnt,
                                                int* bsum) {
  __shared__ int sh[256];
  const int b = blockIdx.x, t = threadIdx.x;
  const int base = b * 1024 + t * 4;
  int s = 0;
  #pragma unroll
  for (int k = 0; k < 4; ++k) {
    const int idx = base + k;
    s += (idx < N_NODES) ? cnt[idx] : 0;
  }
  sh[t] = s; __syncthreads();
  for (int o = 128; o > 0; o >>= 1) {
    if (t < o) sh[t] += sh[t + o];
    __syncthreads();
  }
  if (t == 0) bsum[b] = sh[0];
}

__global__ __launch_bounds__(256) void k_scan_c2(const int* __restrict__ cnt,
                                                 const int* __restrict__ bsum,
                                                 int* offv) {
  __shared__ int sh[256];
  __shared__ int base_sh;
  const int b = blockIdx.x, t = threadIdx.x;

  sh[t] = (t < SCAN_NB && t < b) ? bsum[t] : 0;
  __syncthreads();
  for (int o = 128; o > 0; o >>= 1) {
    if (t < o) sh[t] += sh[t + o];
    __syncthreads();
  }
  if (t == 0) base_sh = sh[0];
  __syncthreads();

  const int base = b * 1024 + t * 4;
  int v[4], p[4], s = 0;
  #pragma unroll
  for (int k = 0; k < 4; ++k) {
    const int idx = base + k;
    v[k] = (idx < N_NODES) ? cnt[idx] : 0;
    p[k] = s; s += v[k];
  }
  sh[t] = s; __syncthreads();
  const int tot = s;
  for (int o = 1; o < 256; o <<= 1) {
    const int tv = (t >= o) ? sh[t - o] : 0;
    __syncthreads();
    sh[t] += tv;
    __syncthreads();
  }
  const int gb = base_sh + (sh[t] - tot);
  #pragma unroll
  for (int k = 0; k < 4; ++k) {
    const int idx = base + k;
    if (idx < N_NODES) offv[idx] = gb + p[k];
  }
}

// place: psrc[j] = src row; ea_s[j] = bf16(ea[e]) written to SORTED position.
// ea_s rows are 64B lines -> full-line scatter writes (no RMW, no latency
// chain); sagg's ea read becomes sequential.
__global__ __launch_bounds__(256) void k_place5(
    const int* __restrict__ ei, const int* __restrict__ offv,
    const int* __restrict__ slot, const float* __restrict__ ea,
    int* __restrict__ psrc, short* __restrict__ ea_s)
{
  const int e = blockIdx.x * 256 + threadIdx.x;
  if (e < N_EDGES) {
    const int j = offv[ei[N_EDGES + e]] + slot[e];
    psrc[j] = ei[e];
    #pragma unroll
    for (int h = 0; h < 4; ++h) {
      const float4 w0 = *(const float4*)&ea[(size_t)e * D_EDGE + h * 8];
      const float4 w1 = *(const float4*)&ea[(size_t)e * D_EDGE + h * 8 + 4];
      bf16x8 o = { f2b(w0.x), f2b(w0.y), f2b(w0.z), f2b(w0.w),
                   f2b(w1.x), f2b(w1.y), f2b(w1.z), f2b(w1.w) };
      *(bf16x8*)&ea_s[(size_t)j * D_EDGE + h * 8] = o;
    }
  }
}

// ===========================================================================
// S aggregation (round-7 shape, upgraded):
//   gtid < N*16 : x-part, 16 thr/node.  4-deep preloaded chunk loop -> 4
//                 outstanding random 256B row-gathers per group.
//   else        : ea-part, 4 thr/node.  SEQUENTIAL coalesced read of ea_s.
// ===========================================================================
__global__ __launch_bounds__(256) void k_sagg4(
    const int* __restrict__ offv, const int* __restrict__ cnt,
    const int* __restrict__ psrc, const short* __restrict__ ea_s,
    short* __restrict__ AF)
{
  const int gtid = blockIdx.x * 256 + threadIdx.x;
  if (gtid < N_NODES * 16) {
    const int node = gtid >> 4;
    const int oct8 = (gtid & 15) << 3;
    const int s0 = offv[node];
    const int s1 = s0 + cnt[node];
    float a[8] = {};
    int j = s0;
    while (j < s1) {
      const int rem = s1 - j;
      bf16x8 v0, v1, v2, v3;
      v0 = *(const bf16x8*)&AF[(size_t)psrc[j] * KTOT + oct8];
      if (rem > 1) v1 = *(const bf16x8*)&AF[(size_t)psrc[j + 1] * KTOT + oct8];
      if (rem > 2) v2 = *(const bf16x8*)&AF[(size_t)psrc[j + 2] * KTOT + oct8];
      if (rem > 3) v3 = *(const bf16x8*)&AF[(size_t)psrc[j + 3] * KTOT + oct8];
      #pragma unroll
      for (int k = 0; k < 8; ++k) a[k] += b2f(v0[k]);
      if (rem > 1) {
        #pragma unroll
        for (int k = 0; k < 8; ++k) a[k] += b2f(v1[k]);
      }
      if (rem > 2) {
        #pragma unroll
        for (int k = 0; k < 8; ++k) a[k] += b2f(v2[k]);
      }
      if (rem > 3) {
        #pragma unroll
        for (int k = 0; k < 8; ++k) a[k] += b2f(v3[k]);
      }
      j += 4;
    }
    bf16x8 o;
    #pragma unroll
    for (int k = 0; k < 8; ++k) o[k] = f2b(a[k]);
    *(bf16x8*)&AF[(size_t)node * KTOT + 128 + oct8] = o;
  } else {
    const int t2 = gtid - N_NODES * 16;       // 0 .. N_NODES*4
    const int node = t2 >> 2;
    const int q8   = (t2 & 3) << 3;           // 8 bf16 = 16B
    const int s0 = offv[node];
    const int s1 = s0 + cnt[node];
    float a[8] = {};
    for (int j = s0; j < s1; ++j) {
      const bf16x8 v = *(const bf16x8*)&ea_s[(size_t)j * D_EDGE + q8];
      #pragma unroll
      for (int k = 0; k < 8; ++k) a[k] += b2f(v[k]);
    }
    bf16x8 o;
    #pragma unroll
    for (int k = 0; k < 8; ++k) o[k] = f2b(a[k]);
    *(bf16x8*)&AF[(size_t)node * KTOT + 256 + q8] = o;
  }
}

// ===========================================================================
// Output GEMM: out = AF @ Wc + cnt*bc + b2.
//   BM=64 (grid 3125, exact), K=288 in 3x96 phases, LDS 39.9KB -> 4 blocks/CU.
//   Epilogue via LDS -> coalesced float4 row stores.  (round-5/7 proven)
// ===========================================================================
#define LDP 104   // 96+8 bf16: 208B rows -> 2-way bank alias only (free)

__global__ __launch_bounds__(256, 4) void k_out2(
    const short* __restrict__ AF, const short* __restrict__ WcT,
    const float* __restrict__ bc, const float* __restrict__ b2,
    const int* __restrict__ cnt, float* __restrict__ out)
{
  __shared__ short smem[64 * LDP + 128 * LDP];   // 39936 B
  short* lA = smem;
  short* lB = smem + 64 * LDP;
  const int tid = threadIdx.x;
  const int n0  = blockIdx.x * 64;

  const int lane = tid & 63;
  const int wid  = tid >> 6;
  const int wm = wid >> 1, wn = wid & 1;          // 2x2 waves, 32x64 out each
  const int lrow = lane & 15;
  const int lk   = (lane >> 4) << 3;

  f32x4 acc[2][4] = {};

  #pragma unroll
  for (int p = 0; p < 3; ++p) {
    for (int i = tid; i < 1536; i += 256) {       // lB: 128 rows x 12 octs
      const int n = i / 12, ck = (i % 12) << 3;
      *(bf16x8*)&lB[n * LDP + ck] = *(const bf16x8*)&WcT[n * KTOT + p * 96 + ck];
    }
    for (int i = tid; i < 768; i += 256) {        // lA: 64 rows x 12 octs
      const int m = i / 12, ck = (i % 12) << 3;
      *(bf16x8*)&lA[m * LDP + ck] = *(const bf16x8*)&AF[(size_t)(n0 + m) * KTOT + p * 96 + ck];
    }
    __syncthreads();
    #pragma unroll
    for (int kt = 0; kt < 3; ++kt) {
      const int ks = kt * 32 + lk;
      bf16x8 af[2], bfr[4];
      #pragma unroll
      for (int i = 0; i < 2; ++i)
        af[i]  = *(const bf16x8*)&lA[(wm * 32 + i * 16 + lrow) * LDP + ks];
      #pragma unroll
      for (int j = 0; j < 4; ++j)
        bfr[j] = *(const bf16x8*)&lB[(wn * 64 + j * 16 + lrow) * LDP + ks];
      #pragma unroll
      for (int i = 0; i < 2; ++i)
        #pragma unroll
        for (int j = 0; j < 4; ++j)
          acc[i][j] = __builtin_amdgcn_mfma_f32_16x16x32_bf16(af[i], bfr[j], acc[i][j], 0, 0, 0);
    }
    __syncthreads();
  }

  // ---- epilogue: acc + cnt*bc + b2 -> LDS f32 [64][128] -> coalesced stores
  float* lf = (float*)smem;                       // 32768 B <= 39936 B
  const int rb = wm * 32 + ((lane >> 4) << 2);
  const int cb = wn * 64 + lrow;
  float bcv[4], b2v[4];
  #pragma unroll
  for (int j = 0; j < 4; ++j) {
    bcv[j] = bc[cb + j * 16];
    b2v[j] = b2[cb + j * 16];
  }
  #pragma unroll
  for (int i = 0; i < 2; ++i) {
    #pragma unroll
    for (int r = 0; r < 4; ++r) {
      const int row = rb + i * 16 + r;
      const float cf = (float)cnt[n0 + row];
      #pragma unroll
      for (int j = 0; j < 4; ++j)
        lf[row * 128 + cb + j * 16] = acc[i][j][r] + cf * bcv[j] + b2v[j];
    }
  }
  __syncthreads();
  #pragma unroll
  for (int u = 0; u < 8; ++u) {
    const int idx = tid + u * 256;                // 2048 float4s
    const int row = idx >> 5, f4 = (idx & 31) << 2;
    *(float4*)&out[(size_t)(n0 + row) * HIDDEN + f4] = *(const float4*)&lf[row * 128 + f4];
  }
}

extern "C" void kernel_launch(void* const* d_in, const int* in_sizes, int n_in,
                              void* d_out, int out_size, void* d_ws, size_t ws_size,
                              hipStream_t stream) {
  const float* x  = (const float*)d_in[0];
  const int*   ei = (const int*)d_in[1];
  const float* ea = (const float*)d_in[2];
  const float* W1 = (const float*)d_in[5];
  const float* b1 = (const float*)d_in[6];
  const float* W2 = (const float*)d_in[7];
  const float* b2 = (const float*)d_in[8];
  float* out = (float*)d_out;

  const size_t AF_B   = (size_t)N_NODES * KTOT * 2;   // 115,200,000
  const size_t WCT_B  = 128 * KTOT * 2;               //      73,728
  const size_t BC_B   = 512;
  const size_t CNT_B  = (size_t)N_NODES * 4;          //     800,000
  const size_t SLOT_B = (size_t)N_EDGES * 4;          //   2,560,000
  const size_t PSRC_B = (size_t)N_EDGES * 4;          //   2,560,000
  const size_t EAS_B  = (size_t)N_EDGES * D_EDGE * 2; //  40,960,000

  const size_t o_AF   = 0;
  const size_t o_wct  = o_AF + AF_B;
  const size_t o_bc   = o_wct + WCT_B;
  const size_t o_cnt  = o_bc + BC_B;
  const size_t o_off  = o_cnt + CNT_B;
  const size_t o_slot = o_off + CNT_B;
  const size_t o_psrc = o_slot + SLOT_B;
  const size_t o_eas  = o_psrc + PSRC_B;
  const size_t o_bsum = o_eas + EAS_B;
  // total ~163.9 MB (round-2's CSR plan ran at ~170.7 MB -> fits)

  short* AF   = (short*)((char*)d_ws + o_AF);
  short* WcT  = (short*)((char*)d_ws + o_wct);
  float* bc   = (float*)((char*)d_ws + o_bc);
  int*   cnt  = (int*)((char*)d_ws + o_cnt);
  int*   offv = (int*)((char*)d_ws + o_off);
  int*   slot = (int*)((char*)d_ws + o_slot);
  int*   psrc = (int*)((char*)d_ws + o_psrc);
  short* ea_s = (short*)((char*)d_ws + o_eas);
  int*   bsum = (int*)((char*)d_ws + o_bsum);

  hipMemsetAsync(cnt, 0, CNT_B, stream);
  k_prep<<<PREP_NB + HIST_NB + WC_NB, 256, 0, stream>>>(
      x, AF, ei, cnt, slot, W1, b1, W2, WcT, bc);

  k_scan_a <<<SCAN_NB, 256, 0, stream>>>(cnt, bsum);
  k_scan_c2<<<SCAN_NB, 256, 0, stream>>>(cnt, bsum, offv);
  k_place5 <<<(N_EDGES + 255) / 256, 256, 0, stream>>>(ei, offv, slot, ea, psrc, ea_s);

  k_sagg4<<<(N_NODES * 20) / 256, 256, 0, stream>>>(offv, cnt, psrc, ea_s, AF);
  k_out2 <<<N_NODES / 64, 256, 0, stream>>>(AF, WcT, bc, b2, cnt, out);
}